// Round 14
// baseline (211.827 us; speedup 1.0000x reference)
//
#include <hip/hip_runtime.h>
#include <stdint.h>
#include <stddef.h>

// ---------------------------------------------------------------------------
// PVT-style SR-attention, MI355X bf16 MFMA pipeline.
//   flash attention: swapped-QK^T 32x32x16, dbuf LDS, reg staging (r10),
//   UNSHIFTED softmax with SCL pre-folded into Q-projection, depth-2 pipeline
//   (r13-verified cadence), QW64: each wave owns 64 q-rows (2 B-groups) so
//   16 ds_read_b128 feed 64 MFMAs (2x LDS amortization), grid 512.
//   T12 cvt_pk+permlane pack, T5 setprio, XCD swizzle.
//   K+V projections fused; V-projection writes V^T directly.
// ---------------------------------------------------------------------------

using bf16x8 = __attribute__((ext_vector_type(8))) short;
using f32x4  = __attribute__((ext_vector_type(4))) float;
using f32x16 = __attribute__((ext_vector_type(16))) float;
using u16x4  = __attribute__((ext_vector_type(4))) unsigned short;
using u32x4  = __attribute__((ext_vector_type(4))) uint32_t;

#define ATT_SCL_L2E 0.18033688011112043f   // (1/sqrt(64)) * log2(e)

#if defined(__has_builtin)
#if __has_builtin(__builtin_amdgcn_exp2f)
#define FAST_EXP2(x) __builtin_amdgcn_exp2f(x)
#endif
#endif
#ifndef FAST_EXP2
extern "C" __device__ float __ocml_native_exp2_f32(float);
#define FAST_EXP2(x) __ocml_native_exp2_f32(x)
#endif

__device__ __forceinline__ unsigned short f2bf(float f) {
  union { float f; uint32_t u; } v; v.f = f;
  uint32_t r = v.u + 0x7fffu + ((v.u >> 16) & 1u);   // RNE
  return (unsigned short)(r >> 16);
}

__device__ __forceinline__ uint32_t cvt_pk_bf16(float lo, float hi) {
  uint32_t r;
  asm("v_cvt_pk_bf16_f32 %0, %1, %2" : "=v"(r) : "v"(lo), "v"(hi));
  return r;
}

// v_permlane32_swap_b32: a[32+i] <-> b[i]. ONLY used with provably-distinct
// values (P-pack, epilogue) — verified r3-r5/r9/r10/r12/r13. Never a==b.
__device__ __forceinline__ void plane32_swap(uint32_t& a, uint32_t& b) {
  asm("v_permlane32_swap_b32 %0, %1" : "+v"(a), "+v"(b));
}

// ---------------- cast fp32 -> bf16 (8 elems/thread) ----------------
__global__ __launch_bounds__(256)
void cast_bf16_kernel(const float* __restrict__ in, unsigned short* __restrict__ out, int n) {
  int i = (blockIdx.x * 256 + threadIdx.x) * 8;
  if (i >= n) return;
  float4 a = *(const float4*)(in + i);
  float4 b = *(const float4*)(in + i + 4);
  u16x4 r0 = {f2bf(a.x), f2bf(a.y), f2bf(a.z), f2bf(a.w)};
  u16x4 r1 = {f2bf(b.x), f2bf(b.y), f2bf(b.z), f2bf(b.w)};
  *(u16x4*)(out + i) = r0;
  *(u16x4*)(out + i + 4) = r1;
}

// fused cast of the 4 projection weights (each 1M elems; dsts contiguous)
struct WPtrs { const float* p0; const float* p1; const float* p2; const float* p3; };
__global__ __launch_bounds__(256)
void cast4_bf16_kernel(WPtrs in, unsigned short* __restrict__ out) {
  int which = blockIdx.x >> 9;                       // 512 blocks per tensor
  int i = ((blockIdx.x & 511) * 256 + threadIdx.x) * 8;
  const float* src = (which == 0) ? in.p0 : (which == 1) ? in.p1
                   : (which == 2) ? in.p2 : in.p3;
  unsigned short* dst = out + (size_t)which * 1048576;
  float4 a = *(const float4*)(src + i);
  float4 b = *(const float4*)(src + i + 4);
  u16x4 r0 = {f2bf(a.x), f2bf(a.y), f2bf(a.z), f2bf(a.w)};
  u16x4 r1 = {f2bf(b.x), f2bf(b.y), f2bf(b.z), f2bf(b.w)};
  *(u16x4*)(dst + i) = r0;
  *(u16x4*)(dst + i + 4) = r1;
}

// ---------------- depthwise conv1d k=3 s=2 p=1 -> bf16 xd ----------------
__global__ __launch_bounds__(256)
void conv_ds_kernel(const float* __restrict__ x, const float* __restrict__ cw,
                    const float* __restrict__ cb, unsigned short* __restrict__ xd) {
  int row = blockIdx.x;            // b*2048 + m
  int b = row >> 11, m = row & 2047;
  int c = threadIdx.x * 4;
  const float* xb = x + (size_t)b * 4096 * 1024;
  int n0 = 2 * m - 1;
  float4 x0 = {0.f, 0.f, 0.f, 0.f};
  if (n0 >= 0) x0 = *(const float4*)(xb + (size_t)n0 * 1024 + c);
  float4 x1 = *(const float4*)(xb + (size_t)(2 * m) * 1024 + c);
  float4 x2 = *(const float4*)(xb + (size_t)(2 * m + 1) * 1024 + c);
  float4 w0 = *(const float4*)(cw + c * 3);
  float4 w1 = *(const float4*)(cw + c * 3 + 4);
  float4 w2 = *(const float4*)(cw + c * 3 + 8);
  float4 bb = *(const float4*)(cb + c);
  float r0 = x0.x * w0.x + x1.x * w0.y + x2.x * w0.z + bb.x;
  float r1 = x0.y * w0.w + x1.y * w1.x + x2.y * w1.y + bb.y;
  float r2 = x0.z * w1.z + x1.z * w1.w + x2.z * w2.x + bb.z;
  float r3 = x0.w * w2.y + x1.w * w2.z + x2.w * w2.w + bb.w;
  u16x4 r = {f2bf(r0), f2bf(r1), f2bf(r2), f2bf(r3)};
  *(u16x4*)(xd + (size_t)row * 1024 + c) = r;
}

// ---------------- bf16 GEMM  out[M,N] = A[M,K] @ W[N,K]^T + bias ----------------
// OUT_MODE: 0 = f32 row-major; 1 = bf16 row-major SCALED by ATT_SCL_L2E (q only);
//           3 = fused KV: cols 0-1023 -> bf16 [M,1024] (out,bias),
//                         cols 1024-2047 -> V^T [(b*1024+col')*2048+kv] (out2,bias2)
template<int OUT_MODE>
__global__ __launch_bounds__(256)
void gemm_bt(const unsigned short* __restrict__ A, const unsigned short* __restrict__ W,
             const float* __restrict__ bias, const float* __restrict__ bias2,
             void* __restrict__ out, void* __restrict__ out2,
             int M, int N, int K) {
  __shared__ unsigned short As[128 * 32];
  __shared__ unsigned short Bs[128 * 32];
  const int tid = threadIdx.x;
  const int w = tid >> 6, lane = tid & 63;
  const int nbn = N >> 7;
  const int bm = blockIdx.x / nbn, bn = blockIdx.x % nbn;
  const int wr = w >> 1, wc = w & 1;
  const int l15 = lane & 15, l4 = lane >> 4;

  f32x4 acc[4][4];
#pragma unroll
  for (int m = 0; m < 4; ++m)
#pragma unroll
    for (int n = 0; n < 4; ++n) acc[m][n] = (f32x4)0.0f;

  const int arow = bm * 128 + w * 16 + (lane >> 2);
  const int brow = bn * 128 + w * 16 + (lane >> 2);
  const int kcol = (lane & 3) * 8;

  for (int kt = 0; kt < K; kt += 32) {
#pragma unroll
    for (int p = 0; p < 2; ++p) {
      __builtin_amdgcn_global_load_lds(
          (const __attribute__((address_space(1))) void*)(A + (size_t)(arow + p * 64) * K + kt + kcol),
          (__attribute__((address_space(3))) void*)(As + p * 2048 + w * 512), 16, 0, 0);
      __builtin_amdgcn_global_load_lds(
          (const __attribute__((address_space(1))) void*)(W + (size_t)(brow + p * 64) * K + kt + kcol),
          (__attribute__((address_space(3))) void*)(Bs + p * 2048 + w * 512), 16, 0, 0);
    }
    __syncthreads();
    bf16x8 af[4], bf[4];
#pragma unroll
    for (int m = 0; m < 4; ++m) af[m] = *(const bf16x8*)(As + (wr * 64 + m * 16 + l15) * 32 + l4 * 8);
#pragma unroll
    for (int n = 0; n < 4; ++n) bf[n] = *(const bf16x8*)(Bs + (wc * 64 + n * 16 + l15) * 32 + l4 * 8);
#pragma unroll
    for (int m = 0; m < 4; ++m)
#pragma unroll
      for (int n = 0; n < 4; ++n)
        acc[m][n] = __builtin_amdgcn_mfma_f32_16x16x32_bf16(af[m], bf[n], acc[m][n], 0, 0, 0);
    __syncthreads();
  }

  const bool vregion = (OUT_MODE == 3) && (bn >= 8);
#pragma unroll
  for (int n = 0; n < 4; ++n) {
    int col = bn * 128 + wc * 64 + n * 16 + l15;
    float bv = vregion ? bias2[col - 1024] : bias[col];
#pragma unroll
    for (int m = 0; m < 4; ++m) {
      int row0 = bm * 128 + wr * 64 + m * 16 + l4 * 4;
      if (vregion) {
        int b = row0 >> 11, kv = row0 & 2047;
        u16x4 r = {f2bf(acc[m][n][0] + bv), f2bf(acc[m][n][1] + bv),
                   f2bf(acc[m][n][2] + bv), f2bf(acc[m][n][3] + bv)};
        *(u16x4*)((unsigned short*)out2 + ((size_t)(b * 1024 + (col - 1024))) * 2048 + kv) = r;
      } else if (OUT_MODE == 1) {
        // q-projection: fold attention scale (pre-exp2) into the output
#pragma unroll
        for (int i = 0; i < 4; ++i)
          ((unsigned short*)out)[(size_t)(row0 + i) * N + col] =
              f2bf((acc[m][n][i] + bv) * ATT_SCL_L2E);
      } else if (OUT_MODE == 3) {
#pragma unroll
        for (int i = 0; i < 4; ++i)
          ((unsigned short*)out)[(size_t)(row0 + i) * 1024 + col] = f2bf(acc[m][n][i] + bv);
      } else {
#pragma unroll
        for (int i = 0; i < 4; ++i)
          ((float*)out)[(size_t)(row0 + i) * N + col] = acc[m][n][i] + bv;
      }
    }
  }
}

// ---------------- flash attention (QW64, depth-2 pipeline) ----------------
__global__ __launch_bounds__(256)
void flash_attn_kernel(const unsigned short* __restrict__ q,
                       const unsigned short* __restrict__ k,
                       const unsigned short* __restrict__ vt,
                       unsigned short* __restrict__ o) {
  // XCD-chunked bijective swizzle: 512 wgs / 8 XCDs; each XCD owns 4 (h,b) pairs.
  const int bid = blockIdx.x;
  const int lin = (bid & 7) * 64 + (bid >> 3);
  const int qb = lin & 15;          // 16 q-blocks of 256 rows
  const int hb = lin >> 4;
  const int h = hb & 15, b = hb >> 4;

  const int tid = threadIdx.x;
  const int w = tid >> 6, lane = tid & 63;
  const int l31 = lane & 31, hi = lane >> 5;

  // double-buffered K [kv=64][d=64] and V^T [d=64][kv=64]; 16B-chunk XOR swizzle
  __shared__ unsigned short Ks[2][64 * 64];
  __shared__ unsigned short Vs[2][64 * 64];

  const size_t C = 1024;
  const int qrow0 = b * 4096 + qb * 256 + w * 64;   // wave's 64 q-rows
  const int rqA = qrow0 + l31, rqB = qrow0 + 32 + l31;

  // Q (pre-scaled by SCL_L2E in projection) as MFMA B-operand, two groups
  bf16x8 qfA[4], qfB[4];
#pragma unroll
  for (int ks = 0; ks < 4; ++ks) {
    qfA[ks] = *(const bf16x8*)(q + (size_t)rqA * C + h * 64 + ks * 16 + hi * 8);
    qfB[ks] = *(const bf16x8*)(q + (size_t)rqB * C + h * 64 + ks * 16 + hi * 8);
  }

  f32x16 o0A = (f32x16)0.0f, o1A = (f32x16)0.0f;
  f32x16 o0B = (f32x16)0.0f, o1B = (f32x16)0.0f;
  float lrunA = 0.f, lrunB = 0.f;

  // ---- conflict-free staging map (r10-proven): 8-lane phase -> 8 rows ----
  const int srow = (tid & 7) | ((tid >> 5) << 3);   // 0..63
  const int sc2  = (tid >> 3) & 3;                  // 0..3
  const int sxor = (srow & 7);                      // chunk XOR for this row
  const unsigned short* kbase = k  + ((size_t)(b * 2048 + srow)) * C + h * 64;
  const unsigned short* vbase = vt + ((size_t)(b * 1024 + h * 64 + srow)) * 2048;

  const int r0 = l31, r1 = 32 + l31;
  const int x0c = (r0 & 7) * 8, x1c = (r1 & 7) * 8;

  // exp + T12 pack for both groups: s -> pw[0..3]=A, pw[4..7]=B
  auto exppack = [&](f32x16& a0, f32x16& a1, f32x16& b0, f32x16& b1, u32x4 (&pw)[8]) {
    float rsA = 0.f, rsB = 0.f;
#pragma unroll
    for (int i = 0; i < 16; ++i) {
      float pa0 = FAST_EXP2(a0[i]);
      float pa1 = FAST_EXP2(a1[i]);
      float pb0 = FAST_EXP2(b0[i]);
      float pb1 = FAST_EXP2(b1[i]);
      a0[i] = pa0; a1[i] = pa1; b0[i] = pb0; b1[i] = pb1;
      rsA += pa0 + pa1; rsB += pb0 + pb1;
    }
    lrunA += rsA; lrunB += rsB;
#pragma unroll
    for (int g = 0; g < 2; ++g) {
      f32x16& s0 = g ? b0 : a0;
      f32x16& s1 = g ? b1 : a1;
#pragma unroll
      for (int hh = 0; hh < 2; ++hh) {
#pragma unroll
        for (int cp = 0; cp < 2; ++cp) {
#pragma unroll
          for (int e = 0; e < 2; ++e) {
            float xa0 = (hh == 0) ? s0[8 * cp + 2 * e]     : s1[8 * cp + 2 * e];
            float xa1 = (hh == 0) ? s0[8 * cp + 2 * e + 1] : s1[8 * cp + 2 * e + 1];
            float xb0 = (hh == 0) ? s0[8 * cp + 4 + 2 * e]     : s1[8 * cp + 4 + 2 * e];
            float xb1 = (hh == 0) ? s0[8 * cp + 4 + 2 * e + 1] : s1[8 * cp + 4 + 2 * e + 1];
            uint32_t wa = cvt_pk_bf16(xa0, xa1);
            uint32_t wb = cvt_pk_bf16(xb0, xb1);
            plane32_swap(wa, wb);
            pw[g * 4 + 2 * hh + cp][e]     = wa;
            pw[g * 4 + 2 * hh + cp][e + 2] = wb;
          }
        }
      }
    }
  };

  bf16x8 krg[2], vrg[2], tmp[2];
  // prologue staging: K(0)->Ks[0], K(1)->Ks[1], V(0)->Vs[0]; regs K(2), V(1)
#pragma unroll
  for (int j = 0; j < 2; ++j) tmp[j] = *(const bf16x8*)(kbase + (sc2 + 4 * j) * 8);
#pragma unroll
  for (int j = 0; j < 2; ++j)
    *(bf16x8*)(&Ks[0][srow * 64 + (((sc2 + 4 * j) ^ sxor) * 8)]) = tmp[j];
#pragma unroll
  for (int j = 0; j < 2; ++j) tmp[j] = *(const bf16x8*)(kbase + (size_t)64 * C + (sc2 + 4 * j) * 8);
#pragma unroll
  for (int j = 0; j < 2; ++j)
    *(bf16x8*)(&Ks[1][srow * 64 + (((sc2 + 4 * j) ^ sxor) * 8)]) = tmp[j];
#pragma unroll
  for (int j = 0; j < 2; ++j) tmp[j] = *(const bf16x8*)(vbase + (sc2 + 4 * j) * 8);
#pragma unroll
  for (int j = 0; j < 2; ++j)
    *(bf16x8*)(&Vs[0][srow * 64 + (((sc2 + 4 * j) ^ sxor) * 8)]) = tmp[j];
#pragma unroll
  for (int j = 0; j < 2; ++j) {
    krg[j] = *(const bf16x8*)(kbase + (size_t)128 * C + (sc2 + 4 * j) * 8);
    vrg[j] = *(const bf16x8*)(vbase + 64 + (sc2 + 4 * j) * 8);
  }
  __syncthreads();

  // ---- prologue compute: QK(0) both groups; exp/pack(0) -> pwA ----
  u32x4 pwA[8], pwB[8];
  {
    f32x16 sA0 = (f32x16)0.0f, sA1 = (f32x16)0.0f;
    f32x16 sB0 = (f32x16)0.0f, sB1 = (f32x16)0.0f;
    __builtin_amdgcn_s_setprio(1);
#pragma unroll
    for (int ks = 0; ks < 4; ++ks) {
      int coff = ks * 16 + hi * 8;
      bf16x8 kf0 = *(const bf16x8*)(&Ks[0][r0 * 64 + (coff ^ x0c)]);
      bf16x8 kf1 = *(const bf16x8*)(&Ks[0][r1 * 64 + (coff ^ x1c)]);
      sA0 = __builtin_amdgcn_mfma_f32_32x32x16_bf16(kf0, qfA[ks], sA0, 0, 0, 0);
      sA1 = __builtin_amdgcn_mfma_f32_32x32x16_bf16(kf1, qfA[ks], sA1, 0, 0, 0);
      sB0 = __builtin_amdgcn_mfma_f32_32x32x16_bf16(kf0, qfB[ks], sB0, 0, 0, 0);
      sB1 = __builtin_amdgcn_mfma_f32_32x32x16_bf16(kf1, qfB[ks], sB1, 0, 0, 0);
    }
    __builtin_amdgcn_s_setprio(0);
    exppack(sA0, sA1, sB0, sB1, pwA);
  }
  __syncthreads();   // all waves done reading Ks[0] before iter-0 stages K(2)

  // ---- depth-2 pipelined main loop (r13-verified cadence) ----
  auto body = [&](int t, u32x4 (&pwC)[8], u32x4 (&pwN)[8]) {
    const unsigned short* Vc = Vs[t & 1];
    f32x16 sA0 = (f32x16)0.0f, sA1 = (f32x16)0.0f;
    f32x16 sB0 = (f32x16)0.0f, sB1 = (f32x16)0.0f;

    __builtin_amdgcn_s_setprio(1);
    if (t < 31) {   // QK(t+1): reads Ks[(t+1)&1], untouched by iter-t staging
      const unsigned short* Kn = Ks[(t + 1) & 1];
#pragma unroll
      for (int ks = 0; ks < 4; ++ks) {
        int coff = ks * 16 + hi * 8;
        bf16x8 kf0 = *(const bf16x8*)(Kn + r0 * 64 + (coff ^ x0c));
        bf16x8 kf1 = *(const bf16x8*)(Kn + r1 * 64 + (coff ^ x1c));
        sA0 = __builtin_amdgcn_mfma_f32_32x32x16_bf16(kf0, qfA[ks], sA0, 0, 0, 0);
        sA1 = __builtin_amdgcn_mfma_f32_32x32x16_bf16(kf1, qfA[ks], sA1, 0, 0, 0);
        sB0 = __builtin_amdgcn_mfma_f32_32x32x16_bf16(kf0, qfB[ks], sB0, 0, 0, 0);
        sB1 = __builtin_amdgcn_mfma_f32_32x32x16_bf16(kf1, qfB[ks], sB1, 0, 0, 0);
      }
    }
    // PV(t): pwC packed last iteration -> independent of this iter's exp
#pragma unroll
    for (int ksv = 0; ksv < 4; ++ksv) {
      bf16x8 pvA = __builtin_bit_cast(bf16x8, pwC[ksv]);
      bf16x8 pvB = __builtin_bit_cast(bf16x8, pwC[4 + ksv]);
      int coff = ksv * 16 + hi * 8;
      bf16x8 vf0 = *(const bf16x8*)(Vc + r0 * 64 + (coff ^ x0c));
      bf16x8 vf1 = *(const bf16x8*)(Vc + r1 * 64 + (coff ^ x1c));
      o0A = __builtin_amdgcn_mfma_f32_32x32x16_bf16(vf0, pvA, o0A, 0, 0, 0);
      o1A = __builtin_amdgcn_mfma_f32_32x32x16_bf16(vf1, pvA, o1A, 0, 0, 0);
      o0B = __builtin_amdgcn_mfma_f32_32x32x16_bf16(vf0, pvB, o0B, 0, 0, 0);
      o1B = __builtin_amdgcn_mfma_f32_32x32x16_bf16(vf1, pvB, o1B, 0, 0, 0);
    }
    __builtin_amdgcn_s_setprio(0);

    // staging (r12/r13-verified cadence): K leads V by one tile
    if (t < 30) {
#pragma unroll
      for (int j = 0; j < 2; ++j)
        *(bf16x8*)(&((unsigned short*)Ks[t & 1])[srow * 64 + (((sc2 + 4 * j) ^ sxor) * 8)]) = krg[j];
    }
    if (t < 31) {
#pragma unroll
      for (int j = 0; j < 2; ++j)
        *(bf16x8*)(&((unsigned short*)Vs[(t + 1) & 1])[srow * 64 + (((sc2 + 4 * j) ^ sxor) * 8)]) = vrg[j];
    }
    if (t < 29) {
#pragma unroll
      for (int j = 0; j < 2; ++j)
        krg[j] = *(const bf16x8*)(kbase + (size_t)(t + 3) * 64 * C + (sc2 + 4 * j) * 8);
    }
    if (t < 30) {
#pragma unroll
      for (int j = 0; j < 2; ++j)
        vrg[j] = *(const bf16x8*)(vbase + (t + 2) * 64 + (sc2 + 4 * j) * 8);
    }

    // exp/pack(t+1): result needed only at next iter's PV
    if (t < 31) exppack(sA0, sA1, sB0, sB1, pwN);

    if (t < 31) __syncthreads();
  };

  for (int tt = 0; tt < 16; ++tt) {
    body(2 * tt,     pwA, pwB);
    body(2 * tt + 1, pwB, pwA);
  }

  // ---- epilogue: normalize, redistribute halves, store both groups ----
  auto store_group = [&](f32x16& g0, f32x16& g1, float lrun, int row) {
    float lsum = lrun + __shfl_xor(lrun, 32);
    const float inv = 1.0f / lsum;
    u32x4 ow[4];
#pragma unroll
    for (int c = 0; c < 4; ++c) {
#pragma unroll
      for (int e = 0; e < 2; ++e) {
        uint32_t wa = cvt_pk_bf16(g0[4 * c + 2 * e] * inv, g0[4 * c + 2 * e + 1] * inv);
        uint32_t wb = cvt_pk_bf16(g1[4 * c + 2 * e] * inv, g1[4 * c + 2 * e + 1] * inv);
        plane32_swap(wa, wb);
        ow[c][e]     = wa;
        ow[c][e + 2] = wb;
      }
    }
    unsigned short* op = o + (size_t)row * C + h * 64 + hi * 32;
#pragma unroll
    for (int ch = 0; ch < 4; ++ch)
      *(u32x4*)(op + ch * 8) = ow[ch];
  };
  store_group(o0A, o1A, lrunA, rqA);
  store_group(o0B, o1B, lrunB, rqB);
}

// ---------------------------------------------------------------------------
extern "C" void kernel_launch(void* const* d_in, const int* in_sizes, int n_in,
                              void* d_out, int out_size, void* d_ws, size_t ws_size,
                              hipStream_t stream) {
  const float* x   = (const float*)d_in[0];
  const float* q_w = (const float*)d_in[1];
  const float* q_b = (const float*)d_in[2];
  const float* k_w = (const float*)d_in[3];
  const float* k_b = (const float*)d_in[4];
  const float* v_w = (const float*)d_in[5];
  const float* v_b = (const float*)d_in[6];
  const float* cw  = (const float*)d_in[7];
  const float* cb  = (const float*)d_in[8];
  const float* o_w = (const float*)d_in[9];
  const float* o_b = (const float*)d_in[10];
  float* out = (float*)d_out;

  unsigned short* ws    = (unsigned short*)d_ws;
  unsigned short* x_bf  = ws;                    // 8388608 (2*4096*1024)
  unsigned short* qw_bf = x_bf + 8388608;        // 4x 1048576, contiguous
  unsigned short* kw_bf = qw_bf + 1048576;       // (qw,kw,vw,ow order)
  unsigned short* vw_bf = kw_bf + 1048576;
  unsigned short* ow_bf = vw_bf + 1048576;
  unsigned short* q_bf  = ow_bf + 1048576;       // 8388608
  unsigned short* xd_bf = q_bf + 8388608;        // 4194304 (2*2048*1024)
  unsigned short* k_bf  = xd_bf + 4194304;
  unsigned short* vt_bf = k_bf + 4194304;        // V^T [B*H, 64, 2048]
  unsigned short* ao_bf = x_bf;                  // alias: x_bf dead after q-GEMM

  cast_bf16_kernel<<<4096, 256, 0, stream>>>(x, x_bf, 8388608);
  WPtrs wp = {q_w, k_w, v_w, o_w};
  cast4_bf16_kernel<<<2048, 256, 0, stream>>>(wp, qw_bf);
  conv_ds_kernel<<<4096, 256, 0, stream>>>(x, cw, cb, xd_bf);

  gemm_bt<1><<<512, 256, 0, stream>>>(x_bf, qw_bf, q_b, nullptr, q_bf, nullptr,
                                      8192, 1024, 1024);
  // fused K+V projection: W rows 0-1023 = k_w, 1024-2047 = v_w
  gemm_bt<3><<<512, 256, 0, stream>>>(xd_bf, kw_bf, k_b, v_b, k_bf, vt_bf,
                                      4096, 2048, 1024);

  flash_attn_kernel<<<512, 256, 0, stream>>>(q_bf, k_bf, vt_bf, ao_bf);

  gemm_bt<0><<<512, 256, 0, stream>>>(ao_bf, ow_bf, o_b, nullptr, out, nullptr,
                                      8192, 1024, 1024);
}

// Round 15
// 194.240 us; speedup vs baseline: 1.0905x; 1.0905x over previous
//
#include <hip/hip_runtime.h>
#include <stdint.h>
#include <stddef.h>

// ---------------------------------------------------------------------------
// PVT-style SR-attention, MI355X bf16 MFMA pipeline.
//   flash attention: r13-verified kernel (swapped-QK^T 32x32x16, dbuf LDS,
//   reg staging, UNSHIFTED softmax scale-folded into Q-projection, depth-2
//   pipeline, T12 pack, T5 setprio, XCD swizzle) — 101.2us, QW64 reverted.
//   conv fused with x->bf16 cast (x read once); GEMMs get XCD block swizzle.
// ---------------------------------------------------------------------------

using bf16x8 = __attribute__((ext_vector_type(8))) short;
using f32x4  = __attribute__((ext_vector_type(4))) float;
using f32x16 = __attribute__((ext_vector_type(16))) float;
using u16x4  = __attribute__((ext_vector_type(4))) unsigned short;
using u32x4  = __attribute__((ext_vector_type(4))) uint32_t;

#define ATT_SCL_L2E 0.18033688011112043f   // (1/sqrt(64)) * log2(e)

#if defined(__has_builtin)
#if __has_builtin(__builtin_amdgcn_exp2f)
#define FAST_EXP2(x) __builtin_amdgcn_exp2f(x)
#endif
#endif
#ifndef FAST_EXP2
extern "C" __device__ float __ocml_native_exp2_f32(float);
#define FAST_EXP2(x) __ocml_native_exp2_f32(x)
#endif

__device__ __forceinline__ unsigned short f2bf(float f) {
  union { float f; uint32_t u; } v; v.f = f;
  uint32_t r = v.u + 0x7fffu + ((v.u >> 16) & 1u);   // RNE
  return (unsigned short)(r >> 16);
}

__device__ __forceinline__ uint32_t cvt_pk_bf16(float lo, float hi) {
  uint32_t r;
  asm("v_cvt_pk_bf16_f32 %0, %1, %2" : "=v"(r) : "v"(lo), "v"(hi));
  return r;
}

// v_permlane32_swap_b32: a[32+i] <-> b[i]. ONLY used with provably-distinct
// values (P-pack, epilogue) — verified r3-r5/r9-r13. Never a==b (r6-r8).
__device__ __forceinline__ void plane32_swap(uint32_t& a, uint32_t& b) {
  asm("v_permlane32_swap_b32 %0, %1" : "+v"(a), "+v"(b));
}

// fused cast of the 4 projection weights (each 1M elems; dsts contiguous)
struct WPtrs { const float* p0; const float* p1; const float* p2; const float* p3; };
__global__ __launch_bounds__(256)
void cast4_bf16_kernel(WPtrs in, unsigned short* __restrict__ out) {
  int which = blockIdx.x >> 9;                       // 512 blocks per tensor
  int i = ((blockIdx.x & 511) * 256 + threadIdx.x) * 8;
  const float* src = (which == 0) ? in.p0 : (which == 1) ? in.p1
                   : (which == 2) ? in.p2 : in.p3;
  unsigned short* dst = out + (size_t)which * 1048576;
  float4 a = *(const float4*)(src + i);
  float4 b = *(const float4*)(src + i + 4);
  u16x4 r0 = {f2bf(a.x), f2bf(a.y), f2bf(a.z), f2bf(a.w)};
  u16x4 r1 = {f2bf(b.x), f2bf(b.y), f2bf(b.z), f2bf(b.w)};
  *(u16x4*)(dst + i) = r0;
  *(u16x4*)(dst + i + 4) = r1;
}

// ---------------- fused depthwise conv1d (k=3 s=2 p=1) + x->bf16 cast ----------------
// block m: reads x rows 2m-1,2m,2m+1; writes xd row m AND x_bf rows 2m,2m+1.
__global__ __launch_bounds__(256)
void conv_cast_kernel(const float* __restrict__ x, const float* __restrict__ cw,
                      const float* __restrict__ cb, unsigned short* __restrict__ xd,
                      unsigned short* __restrict__ x_bf) {
  int row = blockIdx.x;            // b*2048 + m
  int b = row >> 11, m = row & 2047;
  int c = threadIdx.x * 4;
  const float* xb = x + (size_t)b * 4096 * 1024;
  int n0 = 2 * m - 1;
  float4 x0 = {0.f, 0.f, 0.f, 0.f};
  if (n0 >= 0) x0 = *(const float4*)(xb + (size_t)n0 * 1024 + c);
  float4 x1 = *(const float4*)(xb + (size_t)(2 * m) * 1024 + c);
  float4 x2 = *(const float4*)(xb + (size_t)(2 * m + 1) * 1024 + c);
  float4 w0 = *(const float4*)(cw + c * 3);
  float4 w1 = *(const float4*)(cw + c * 3 + 4);
  float4 w2 = *(const float4*)(cw + c * 3 + 8);
  float4 bb = *(const float4*)(cb + c);
  float r0 = x0.x * w0.x + x1.x * w0.y + x2.x * w0.z + bb.x;
  float r1 = x0.y * w0.w + x1.y * w1.x + x2.y * w1.y + bb.y;
  float r2 = x0.z * w1.z + x1.z * w1.w + x2.z * w2.x + bb.z;
  float r3 = x0.w * w2.y + x1.w * w2.z + x2.w * w2.w + bb.w;
  u16x4 r = {f2bf(r0), f2bf(r1), f2bf(r2), f2bf(r3)};
  *(u16x4*)(xd + (size_t)row * 1024 + c) = r;
  // fused cast: rows 2m and 2m+1 of x -> bf16 (each row written exactly once)
  unsigned short* xbf_b = x_bf + (size_t)b * 4096 * 1024;
  u16x4 c1 = {f2bf(x1.x), f2bf(x1.y), f2bf(x1.z), f2bf(x1.w)};
  u16x4 c2 = {f2bf(x2.x), f2bf(x2.y), f2bf(x2.z), f2bf(x2.w)};
  *(u16x4*)(xbf_b + (size_t)(2 * m) * 1024 + c) = c1;
  *(u16x4*)(xbf_b + (size_t)(2 * m + 1) * 1024 + c) = c2;
}

// ---------------- bf16 GEMM  out[M,N] = A[M,K] @ W[N,K]^T + bias ----------------
// OUT_MODE: 0 = f32 row-major; 1 = bf16 row-major SCALED by ATT_SCL_L2E (q only);
//           3 = fused KV: cols 0-1023 -> bf16 [M,1024] (out,bias),
//                         cols 1024-2047 -> V^T [(b*1024+col')*2048+kv] (out2,bias2)
// grid must be 512 (8 XCD chunks of 64) — bijective XCD swizzle applied.
template<int OUT_MODE>
__global__ __launch_bounds__(256)
void gemm_bt(const unsigned short* __restrict__ A, const unsigned short* __restrict__ W,
             const float* __restrict__ bias, const float* __restrict__ bias2,
             void* __restrict__ out, void* __restrict__ out2,
             int M, int N, int K) {
  __shared__ unsigned short As[128 * 32];
  __shared__ unsigned short Bs[128 * 32];
  const int tid = threadIdx.x;
  const int w = tid >> 6, lane = tid & 63;
  const int nbn = N >> 7;
  // T1 XCD swizzle: grid 512 = 8 XCDs x 64 contiguous tiles
  const int swz = (blockIdx.x & 7) * 64 + (blockIdx.x >> 3);
  const int bm = swz / nbn, bn = swz % nbn;
  const int wr = w >> 1, wc = w & 1;
  const int l15 = lane & 15, l4 = lane >> 4;

  f32x4 acc[4][4];
#pragma unroll
  for (int m = 0; m < 4; ++m)
#pragma unroll
    for (int n = 0; n < 4; ++n) acc[m][n] = (f32x4)0.0f;

  const int arow = bm * 128 + w * 16 + (lane >> 2);
  const int brow = bn * 128 + w * 16 + (lane >> 2);
  const int kcol = (lane & 3) * 8;

  for (int kt = 0; kt < K; kt += 32) {
#pragma unroll
    for (int p = 0; p < 2; ++p) {
      __builtin_amdgcn_global_load_lds(
          (const __attribute__((address_space(1))) void*)(A + (size_t)(arow + p * 64) * K + kt + kcol),
          (__attribute__((address_space(3))) void*)(As + p * 2048 + w * 512), 16, 0, 0);
      __builtin_amdgcn_global_load_lds(
          (const __attribute__((address_space(1))) void*)(W + (size_t)(brow + p * 64) * K + kt + kcol),
          (__attribute__((address_space(3))) void*)(Bs + p * 2048 + w * 512), 16, 0, 0);
    }
    __syncthreads();
    bf16x8 af[4], bf[4];
#pragma unroll
    for (int m = 0; m < 4; ++m) af[m] = *(const bf16x8*)(As + (wr * 64 + m * 16 + l15) * 32 + l4 * 8);
#pragma unroll
    for (int n = 0; n < 4; ++n) bf[n] = *(const bf16x8*)(Bs + (wc * 64 + n * 16 + l15) * 32 + l4 * 8);
#pragma unroll
    for (int m = 0; m < 4; ++m)
#pragma unroll
      for (int n = 0; n < 4; ++n)
        acc[m][n] = __builtin_amdgcn_mfma_f32_16x16x32_bf16(af[m], bf[n], acc[m][n], 0, 0, 0);
    __syncthreads();
  }

  const bool vregion = (OUT_MODE == 3) && (bn >= 8);
#pragma unroll
  for (int n = 0; n < 4; ++n) {
    int col = bn * 128 + wc * 64 + n * 16 + l15;
    float bv = vregion ? bias2[col - 1024] : bias[col];
#pragma unroll
    for (int m = 0; m < 4; ++m) {
      int row0 = bm * 128 + wr * 64 + m * 16 + l4 * 4;
      if (vregion) {
        int b = row0 >> 11, kv = row0 & 2047;
        u16x4 r = {f2bf(acc[m][n][0] + bv), f2bf(acc[m][n][1] + bv),
                   f2bf(acc[m][n][2] + bv), f2bf(acc[m][n][3] + bv)};
        *(u16x4*)((unsigned short*)out2 + ((size_t)(b * 1024 + (col - 1024))) * 2048 + kv) = r;
      } else if (OUT_MODE == 1) {
        // q-projection: fold attention scale (pre-exp2) into the output
#pragma unroll
        for (int i = 0; i < 4; ++i)
          ((unsigned short*)out)[(size_t)(row0 + i) * N + col] =
              f2bf((acc[m][n][i] + bv) * ATT_SCL_L2E);
      } else if (OUT_MODE == 3) {
#pragma unroll
        for (int i = 0; i < 4; ++i)
          ((unsigned short*)out)[(size_t)(row0 + i) * 1024 + col] = f2bf(acc[m][n][i] + bv);
      } else {
#pragma unroll
        for (int i = 0; i < 4; ++i)
          ((float*)out)[(size_t)(row0 + i) * N + col] = acc[m][n][i] + bv;
      }
    }
  }
}

// ---------------- flash attention (r13-verified: depth-2 pipeline, 32 q/wave) ----------------
__global__ __launch_bounds__(256)
void flash_attn_kernel(const unsigned short* __restrict__ q,
                       const unsigned short* __restrict__ k,
                       const unsigned short* __restrict__ vt,
                       unsigned short* __restrict__ o) {
  // XCD-chunked bijective swizzle: 1024 wgs / 8 XCDs; each XCD owns 4 (h,b) pairs.
  const int bid = blockIdx.x;
  const int lin = (bid & 7) * 128 + (bid >> 3);
  const int qb = lin & 31;
  const int hb = lin >> 5;
  const int h = hb & 15, b = hb >> 4;

  const int tid = threadIdx.x;
  const int w = tid >> 6, lane = tid & 63;
  const int l31 = lane & 31, hi = lane >> 5;

  // double-buffered K [kv=64][d=64] and V^T [d=64][kv=64]; 16B-chunk XOR swizzle
  __shared__ unsigned short Ks[2][64 * 64];
  __shared__ unsigned short Vs[2][64 * 64];

  const size_t C = 1024;
  const int qrow = b * 4096 + qb * 128 + w * 32 + l31;   // this lane's q-row

  // Q (pre-scaled by SCL_L2E in projection) as MFMA B-operand
  bf16x8 qf[4];
#pragma unroll
  for (int ks = 0; ks < 4; ++ks)
    qf[ks] = *(const bf16x8*)(q + (size_t)qrow * C + h * 64 + ks * 16 + hi * 8);

  f32x16 o0 = (f32x16)0.0f, o1 = (f32x16)0.0f;   // O^T[d][q=l31], d-halves
  float lrun = 0.f;                              // per-half row-sum (merged at end)

  // ---- conflict-free staging map (r10-proven): 8-lane phase -> 8 rows ----
  const int srow = (tid & 7) | ((tid >> 5) << 3);   // 0..63
  const int sc2  = (tid >> 3) & 3;                  // 0..3
  const int sxor = (srow & 7);                      // chunk XOR for this row
  const unsigned short* kbase = k  + ((size_t)(b * 2048 + srow)) * C + h * 64;
  const unsigned short* vbase = vt + ((size_t)(b * 1024 + h * 64 + srow)) * 2048;

  const int r0 = l31, r1 = 32 + l31;
  const int x0c = (r0 & 7) * 8, x1c = (r1 & 7) * 8;

  // exp + T12 pack: s (pre-scaled scores) -> pw fragments; updates lrun
  auto exppack = [&](f32x16& s0, f32x16& s1, u32x4 (&pw)[4]) {
    float rs0 = 0.f, rs1 = 0.f;
#pragma unroll
    for (int i = 0; i < 16; ++i) {
      float p0 = FAST_EXP2(s0[i]);
      float p1 = FAST_EXP2(s1[i]);
      s0[i] = p0; s1[i] = p1;
      rs0 += p0; rs1 += p1;
    }
    lrun += rs0 + rs1;
#pragma unroll
    for (int hh = 0; hh < 2; ++hh) {
#pragma unroll
      for (int cp = 0; cp < 2; ++cp) {
#pragma unroll
        for (int e = 0; e < 2; ++e) {
          float xa0 = (hh == 0) ? s0[8 * cp + 2 * e]     : s1[8 * cp + 2 * e];
          float xa1 = (hh == 0) ? s0[8 * cp + 2 * e + 1] : s1[8 * cp + 2 * e + 1];
          float xb0 = (hh == 0) ? s0[8 * cp + 4 + 2 * e]     : s1[8 * cp + 4 + 2 * e];
          float xb1 = (hh == 0) ? s0[8 * cp + 4 + 2 * e + 1] : s1[8 * cp + 4 + 2 * e + 1];
          uint32_t wa = cvt_pk_bf16(xa0, xa1);
          uint32_t wb = cvt_pk_bf16(xb0, xb1);
          plane32_swap(wa, wb);
          pw[2 * hh + cp][e]     = wa;
          pw[2 * hh + cp][e + 2] = wb;
        }
      }
    }
  };

  bf16x8 krg[2], vrg[2], tmp[2];
  // prologue staging: K(0)->Ks[0], K(1)->Ks[1], V(0)->Vs[0]; regs K(2), V(1)
#pragma unroll
  for (int j = 0; j < 2; ++j) tmp[j] = *(const bf16x8*)(kbase + (sc2 + 4 * j) * 8);
#pragma unroll
  for (int j = 0; j < 2; ++j)
    *(bf16x8*)(&Ks[0][srow * 64 + (((sc2 + 4 * j) ^ sxor) * 8)]) = tmp[j];
#pragma unroll
  for (int j = 0; j < 2; ++j) tmp[j] = *(const bf16x8*)(kbase + (size_t)64 * C + (sc2 + 4 * j) * 8);
#pragma unroll
  for (int j = 0; j < 2; ++j)
    *(bf16x8*)(&Ks[1][srow * 64 + (((sc2 + 4 * j) ^ sxor) * 8)]) = tmp[j];
#pragma unroll
  for (int j = 0; j < 2; ++j) tmp[j] = *(const bf16x8*)(vbase + (sc2 + 4 * j) * 8);
#pragma unroll
  for (int j = 0; j < 2; ++j)
    *(bf16x8*)(&Vs[0][srow * 64 + (((sc2 + 4 * j) ^ sxor) * 8)]) = tmp[j];
#pragma unroll
  for (int j = 0; j < 2; ++j) {
    krg[j] = *(const bf16x8*)(kbase + (size_t)128 * C + (sc2 + 4 * j) * 8);
    vrg[j] = *(const bf16x8*)(vbase + 64 + (sc2 + 4 * j) * 8);
  }
  __syncthreads();

  // ---- prologue compute: QK(0) -> s; exp/pack(0) -> pwA ----
  u32x4 pwA[4], pwB[4];
  {
    f32x16 s0 = (f32x16)0.0f, s1 = (f32x16)0.0f;
    __builtin_amdgcn_s_setprio(1);
#pragma unroll
    for (int ks = 0; ks < 4; ++ks) {
      int coff = ks * 16 + hi * 8;
      bf16x8 kf0 = *(const bf16x8*)(&Ks[0][r0 * 64 + (coff ^ x0c)]);
      bf16x8 kf1 = *(const bf16x8*)(&Ks[0][r1 * 64 + (coff ^ x1c)]);
      s0 = __builtin_amdgcn_mfma_f32_32x32x16_bf16(kf0, qf[ks], s0, 0, 0, 0);
      s1 = __builtin_amdgcn_mfma_f32_32x32x16_bf16(kf1, qf[ks], s1, 0, 0, 0);
    }
    __builtin_amdgcn_s_setprio(0);
    exppack(s0, s1, pwA);
  }
  __syncthreads();   // all waves done reading Ks[0] before iter-0 stages K(2)

  // ---- depth-2 pipelined main loop (r13-verified) ----
  auto body = [&](int t, u32x4 (&pwC)[4], u32x4 (&pwN)[4]) {
    const unsigned short* Vc = Vs[t & 1];
    f32x16 s0 = (f32x16)0.0f, s1 = (f32x16)0.0f;

    __builtin_amdgcn_s_setprio(1);
    if (t < 31) {   // QK(t+1): reads Ks[(t+1)&1], untouched by iter-t staging
      const unsigned short* Kn = Ks[(t + 1) & 1];
#pragma unroll
      for (int ks = 0; ks < 4; ++ks) {
        int coff = ks * 16 + hi * 8;
        bf16x8 kf0 = *(const bf16x8*)(Kn + r0 * 64 + (coff ^ x0c));
        bf16x8 kf1 = *(const bf16x8*)(Kn + r1 * 64 + (coff ^ x1c));
        s0 = __builtin_amdgcn_mfma_f32_32x32x16_bf16(kf0, qf[ks], s0, 0, 0, 0);
        s1 = __builtin_amdgcn_mfma_f32_32x32x16_bf16(kf1, qf[ks], s1, 0, 0, 0);
      }
    }
    // PV(t): pwC packed last iteration -> no dependency on this iter's exp
#pragma unroll
    for (int ksv = 0; ksv < 4; ++ksv) {
      bf16x8 pv = __builtin_bit_cast(bf16x8, pwC[ksv]);
      int coff = ksv * 16 + hi * 8;
      bf16x8 vf0 = *(const bf16x8*)(Vc + r0 * 64 + (coff ^ x0c));
      bf16x8 vf1 = *(const bf16x8*)(Vc + r1 * 64 + (coff ^ x1c));
      o0 = __builtin_amdgcn_mfma_f32_32x32x16_bf16(vf0, pv, o0, 0, 0, 0);
      o1 = __builtin_amdgcn_mfma_f32_32x32x16_bf16(vf1, pv, o1, 0, 0, 0);
    }
    __builtin_amdgcn_s_setprio(0);

    // staging (r12/r13-verified cadence): K leads V by one tile
    if (t < 30) {
#pragma unroll
      for (int j = 0; j < 2; ++j)
        *(bf16x8*)(&((unsigned short*)Ks[t & 1])[srow * 64 + (((sc2 + 4 * j) ^ sxor) * 8)]) = krg[j];
    }
    if (t < 31) {
#pragma unroll
      for (int j = 0; j < 2; ++j)
        *(bf16x8*)(&((unsigned short*)Vs[(t + 1) & 1])[srow * 64 + (((sc2 + 4 * j) ^ sxor) * 8)]) = vrg[j];
    }
    if (t < 29) {
#pragma unroll
      for (int j = 0; j < 2; ++j)
        krg[j] = *(const bf16x8*)(kbase + (size_t)(t + 3) * 64 * C + (sc2 + 4 * j) * 8);
    }
    if (t < 30) {
#pragma unroll
      for (int j = 0; j < 2; ++j)
        vrg[j] = *(const bf16x8*)(vbase + (t + 2) * 64 + (sc2 + 4 * j) * 8);
    }

    // exp/pack(t+1): result needed only at next iter's PV
    if (t < 31) exppack(s0, s1, pwN);

    if (t < 31) __syncthreads();
  };

  for (int tt = 0; tt < 16; ++tt) {
    body(2 * tt,     pwA, pwB);
    body(2 * tt + 1, pwB, pwA);
  }

  // ---- epilogue: merge row-sum halves, normalize, redistribute, store ----
  float lsum = lrun + __shfl_xor(lrun, 32);   // single cross-half merge
  const float inv = 1.0f / lsum;
  u32x4 ow[4];
#pragma unroll
  for (int c = 0; c < 4; ++c) {
#pragma unroll
    for (int e = 0; e < 2; ++e) {
      uint32_t wa = cvt_pk_bf16(o0[4 * c + 2 * e] * inv, o0[4 * c + 2 * e + 1] * inv);
      uint32_t wb = cvt_pk_bf16(o1[4 * c + 2 * e] * inv, o1[4 * c + 2 * e + 1] * inv);
      plane32_swap(wa, wb);
      ow[c][e]     = wa;
      ow[c][e + 2] = wb;
    }
  }
  unsigned short* op = o + (size_t)qrow * C + h * 64 + hi * 32;
#pragma unroll
  for (int ch = 0; ch < 4; ++ch)
    *(u32x4*)(op + ch * 8) = ow[ch];
}

// ---------------------------------------------------------------------------
extern "C" void kernel_launch(void* const* d_in, const int* in_sizes, int n_in,
                              void* d_out, int out_size, void* d_ws, size_t ws_size,
                              hipStream_t stream) {
  const float* x   = (const float*)d_in[0];
  const float* q_w = (const float*)d_in[1];
  const float* q_b = (const float*)d_in[2];
  const float* k_w = (const float*)d_in[3];
  const float* k_b = (const float*)d_in[4];
  const float* v_w = (const float*)d_in[5];
  const float* v_b = (const float*)d_in[6];
  const float* cw  = (const float*)d_in[7];
  const float* cb  = (const float*)d_in[8];
  const float* o_w = (const float*)d_in[9];
  const float* o_b = (const float*)d_in[10];
  float* out = (float*)d_out;

  unsigned short* ws    = (unsigned short*)d_ws;
  unsigned short* x_bf  = ws;                    // 8388608 (2*4096*1024)
  unsigned short* qw_bf = x_bf + 8388608;        // 4x 1048576, contiguous
  unsigned short* kw_bf = qw_bf + 1048576;       // (qw,kw,vw,ow order)
  unsigned short* vw_bf = kw_bf + 1048576;
  unsigned short* ow_bf = vw_bf + 1048576;
  unsigned short* q_bf  = ow_bf + 1048576;       // 8388608
  unsigned short* xd_bf = q_bf + 8388608;        // 4194304 (2*2048*1024)
  unsigned short* k_bf  = xd_bf + 4194304;
  unsigned short* vt_bf = k_bf + 4194304;        // V^T [B*H, 64, 2048]
  unsigned short* ao_bf = x_bf;                  // alias: x_bf dead after q-GEMM

  WPtrs wp = {q_w, k_w, v_w, o_w};
  cast4_bf16_kernel<<<2048, 256, 0, stream>>>(wp, qw_bf);
  conv_cast_kernel<<<4096, 256, 0, stream>>>(x, cw, cb, xd_bf, x_bf);

  gemm_bt<1><<<512, 256, 0, stream>>>(x_bf, qw_bf, q_b, nullptr, q_bf, nullptr,
                                      8192, 1024, 1024);
  // fused K+V projection: W rows 0-1023 = k_w, 1024-2047 = v_w
  gemm_bt<3><<<512, 256, 0, stream>>>(xd_bf, kw_bf, k_b, v_b, k_bf, vt_bf,
                                      4096, 2048, 1024);

  flash_attn_kernel<<<1024, 256, 0, stream>>>(q_bf, k_bf, vt_bf, ao_bf);

  gemm_bt<0><<<512, 256, 0, stream>>>(ao_bf, ow_bf, o_b, nullptr, out, nullptr,
                                      8192, 1024, 1024);
}

// Round 16
// 178.234 us; speedup vs baseline: 1.1885x; 1.0898x over previous
//
#include <hip/hip_runtime.h>
#include <stdint.h>
#include <stddef.h>

// ---------------------------------------------------------------------------
// PVT-style SR-attention, MI355X bf16 MFMA pipeline.
//   flash attention: r13/r15-verified (swapped-QK^T 32x32x16, dbuf LDS, reg
//   staging, UNSHIFTED softmax scale-folded into Q-proj, depth-2 pipeline).
//   q-GEMM + KV-GEMM merged into ONE 1024-block launch (4 blocks/CU: each
//   block's vmcnt(0)+barrier drain hides under the co-resident blocks).
//   prep (weight cast + conv/cast) merged into one launch.
// ---------------------------------------------------------------------------

using bf16x8 = __attribute__((ext_vector_type(8))) short;
using f32x4  = __attribute__((ext_vector_type(4))) float;
using f32x16 = __attribute__((ext_vector_type(16))) float;
using u16x4  = __attribute__((ext_vector_type(4))) unsigned short;
using u32x4  = __attribute__((ext_vector_type(4))) uint32_t;

#define ATT_SCL_L2E 0.18033688011112043f   // (1/sqrt(64)) * log2(e)

#if defined(__has_builtin)
#if __has_builtin(__builtin_amdgcn_exp2f)
#define FAST_EXP2(x) __builtin_amdgcn_exp2f(x)
#endif
#endif
#ifndef FAST_EXP2
extern "C" __device__ float __ocml_native_exp2_f32(float);
#define FAST_EXP2(x) __ocml_native_exp2_f32(x)
#endif

__device__ __forceinline__ unsigned short f2bf(float f) {
  union { float f; uint32_t u; } v; v.f = f;
  uint32_t r = v.u + 0x7fffu + ((v.u >> 16) & 1u);   // RNE
  return (unsigned short)(r >> 16);
}

__device__ __forceinline__ uint32_t cvt_pk_bf16(float lo, float hi) {
  uint32_t r;
  asm("v_cvt_pk_bf16_f32 %0, %1, %2" : "=v"(r) : "v"(lo), "v"(hi));
  return r;
}

// v_permlane32_swap_b32: a[32+i] <-> b[i]. ONLY used with provably-distinct
// values (P-pack, epilogue) — verified r3-r5/r9-r15. Never a==b (r6-r8).
__device__ __forceinline__ void plane32_swap(uint32_t& a, uint32_t& b) {
  asm("v_permlane32_swap_b32 %0, %1" : "+v"(a), "+v"(b));
}

// ---------------- fused prep: weight casts (blocks 0-2047) + conv/cast ----------------
struct WPtrs { const float* p0; const float* p1; const float* p2; const float* p3; };
__global__ __launch_bounds__(256)
void prep_kernel(WPtrs win, unsigned short* __restrict__ wout,
                 const float* __restrict__ x, const float* __restrict__ cw,
                 const float* __restrict__ cb, unsigned short* __restrict__ xd,
                 unsigned short* __restrict__ x_bf) {
  if (blockIdx.x < 2048) {
    int which = blockIdx.x >> 9;                       // 512 blocks per tensor
    int i = ((blockIdx.x & 511) * 256 + threadIdx.x) * 8;
    const float* src = (which == 0) ? win.p0 : (which == 1) ? win.p1
                     : (which == 2) ? win.p2 : win.p3;
    unsigned short* dst = wout + (size_t)which * 1048576;
    float4 a = *(const float4*)(src + i);
    float4 b = *(const float4*)(src + i + 4);
    u16x4 r0 = {f2bf(a.x), f2bf(a.y), f2bf(a.z), f2bf(a.w)};
    u16x4 r1 = {f2bf(b.x), f2bf(b.y), f2bf(b.z), f2bf(b.w)};
    *(u16x4*)(dst + i) = r0;
    *(u16x4*)(dst + i + 4) = r1;
    return;
  }
  // depthwise conv1d k=3 s=2 p=1 + x->bf16 cast (block m handles x rows 2m,2m+1)
  int row = blockIdx.x - 2048;     // b*2048 + m
  int b = row >> 11, m = row & 2047;
  int c = threadIdx.x * 4;
  const float* xb = x + (size_t)b * 4096 * 1024;
  int n0 = 2 * m - 1;
  float4 x0 = {0.f, 0.f, 0.f, 0.f};
  if (n0 >= 0) x0 = *(const float4*)(xb + (size_t)n0 * 1024 + c);
  float4 x1 = *(const float4*)(xb + (size_t)(2 * m) * 1024 + c);
  float4 x2 = *(const float4*)(xb + (size_t)(2 * m + 1) * 1024 + c);
  float4 w0 = *(const float4*)(cw + c * 3);
  float4 w1 = *(const float4*)(cw + c * 3 + 4);
  float4 w2 = *(const float4*)(cw + c * 3 + 8);
  float4 bb = *(const float4*)(cb + c);
  float r0 = x0.x * w0.x + x1.x * w0.y + x2.x * w0.z + bb.x;
  float r1 = x0.y * w0.w + x1.y * w1.x + x2.y * w1.y + bb.y;
  float r2 = x0.z * w1.z + x1.z * w1.w + x2.z * w2.x + bb.z;
  float r3 = x0.w * w2.y + x1.w * w2.z + x2.w * w2.w + bb.w;
  u16x4 r = {f2bf(r0), f2bf(r1), f2bf(r2), f2bf(r3)};
  *(u16x4*)(xd + (size_t)row * 1024 + c) = r;
  unsigned short* xbf_b = x_bf + (size_t)b * 4096 * 1024;
  u16x4 c1 = {f2bf(x1.x), f2bf(x1.y), f2bf(x1.z), f2bf(x1.w)};
  u16x4 c2 = {f2bf(x2.x), f2bf(x2.y), f2bf(x2.z), f2bf(x2.w)};
  *(u16x4*)(xbf_b + (size_t)(2 * m) * 1024 + c) = c1;
  *(u16x4*)(xbf_b + (size_t)(2 * m + 1) * 1024 + c) = c2;
}

// ---------------- bf16 GEMM body  out[M,N] = A[M,K] @ W[N,K]^T + bias ----------------
// OUT_MODE: 0 = f32 row-major; 1 = bf16 row-major SCALED by ATT_SCL_L2E (q);
//           3 = fused KV: cols 0-1023 -> bf16 [M,1024], cols 1024-2047 -> V^T.
// LDS buffers passed in so multiple instantiations share one allocation.
template<int OUT_MODE>
__device__ __forceinline__
void gemm_body(const unsigned short* __restrict__ A, const unsigned short* __restrict__ W,
               const float* __restrict__ bias, const float* __restrict__ bias2,
               void* __restrict__ out, void* __restrict__ out2,
               int N, int K, int swz,
               unsigned short* As, unsigned short* Bs) {
  const int tid = threadIdx.x;
  const int w = tid >> 6, lane = tid & 63;
  const int nbn = N >> 7;
  const int bm = swz / nbn, bn = swz % nbn;
  const int wr = w >> 1, wc = w & 1;
  const int l15 = lane & 15, l4 = lane >> 4;

  f32x4 acc[4][4];
#pragma unroll
  for (int m = 0; m < 4; ++m)
#pragma unroll
    for (int n = 0; n < 4; ++n) acc[m][n] = (f32x4)0.0f;

  const int arow = bm * 128 + w * 16 + (lane >> 2);
  const int brow = bn * 128 + w * 16 + (lane >> 2);
  const int kcol = (lane & 3) * 8;

  for (int kt = 0; kt < K; kt += 32) {
#pragma unroll
    for (int p = 0; p < 2; ++p) {
      __builtin_amdgcn_global_load_lds(
          (const __attribute__((address_space(1))) void*)(A + (size_t)(arow + p * 64) * K + kt + kcol),
          (__attribute__((address_space(3))) void*)(As + p * 2048 + w * 512), 16, 0, 0);
      __builtin_amdgcn_global_load_lds(
          (const __attribute__((address_space(1))) void*)(W + (size_t)(brow + p * 64) * K + kt + kcol),
          (__attribute__((address_space(3))) void*)(Bs + p * 2048 + w * 512), 16, 0, 0);
    }
    __syncthreads();
    bf16x8 af[4], bf[4];
#pragma unroll
    for (int m = 0; m < 4; ++m) af[m] = *(const bf16x8*)(As + (wr * 64 + m * 16 + l15) * 32 + l4 * 8);
#pragma unroll
    for (int n = 0; n < 4; ++n) bf[n] = *(const bf16x8*)(Bs + (wc * 64 + n * 16 + l15) * 32 + l4 * 8);
#pragma unroll
    for (int m = 0; m < 4; ++m)
#pragma unroll
      for (int n = 0; n < 4; ++n)
        acc[m][n] = __builtin_amdgcn_mfma_f32_16x16x32_bf16(af[m], bf[n], acc[m][n], 0, 0, 0);
    __syncthreads();
  }

  const bool vregion = (OUT_MODE == 3) && (bn >= 8);
#pragma unroll
  for (int n = 0; n < 4; ++n) {
    int col = bn * 128 + wc * 64 + n * 16 + l15;
    float bv = vregion ? bias2[col - 1024] : bias[col];
#pragma unroll
    for (int m = 0; m < 4; ++m) {
      int row0 = bm * 128 + wr * 64 + m * 16 + l4 * 4;
      if (vregion) {
        int b = row0 >> 11, kv = row0 & 2047;
        u16x4 r = {f2bf(acc[m][n][0] + bv), f2bf(acc[m][n][1] + bv),
                   f2bf(acc[m][n][2] + bv), f2bf(acc[m][n][3] + bv)};
        *(u16x4*)((unsigned short*)out2 + ((size_t)(b * 1024 + (col - 1024))) * 2048 + kv) = r;
      } else if (OUT_MODE == 1) {
#pragma unroll
        for (int i = 0; i < 4; ++i)
          ((unsigned short*)out)[(size_t)(row0 + i) * N + col] =
              f2bf((acc[m][n][i] + bv) * ATT_SCL_L2E);
      } else if (OUT_MODE == 3) {
#pragma unroll
        for (int i = 0; i < 4; ++i)
          ((unsigned short*)out)[(size_t)(row0 + i) * 1024 + col] = f2bf(acc[m][n][i] + bv);
      } else {
#pragma unroll
        for (int i = 0; i < 4; ++i)
          ((float*)out)[(size_t)(row0 + i) * N + col] = acc[m][n][i] + bv;
      }
    }
  }
}

// merged q-GEMM (blocks 0-511) + KV-GEMM (blocks 512-1023): 4 blocks/CU
__global__ __launch_bounds__(256)
void gemm_qkv_kernel(const unsigned short* __restrict__ x_bf,
                     const unsigned short* __restrict__ qw,
                     const float* __restrict__ q_b,
                     unsigned short* __restrict__ q_bf,
                     const unsigned short* __restrict__ xd,
                     const unsigned short* __restrict__ kvw,
                     const float* __restrict__ k_b, const float* __restrict__ v_b,
                     unsigned short* __restrict__ k_bf,
                     unsigned short* __restrict__ vt_bf) {
  __shared__ unsigned short As[128 * 32];
  __shared__ unsigned short Bs[128 * 32];
  int bid = blockIdx.x;
  if (bid < 512) {
    int swz = (bid & 7) * 64 + (bid >> 3);           // per-half XCD swizzle
    gemm_body<1>(x_bf, qw, q_b, nullptr, q_bf, nullptr, 1024, 1024, swz, As, Bs);
  } else {
    bid -= 512;
    int swz = (bid & 7) * 64 + (bid >> 3);
    gemm_body<3>(xd, kvw, k_b, v_b, k_bf, vt_bf, 2048, 1024, swz, As, Bs);
  }
}

// standalone out-GEMM (r15-verified)
__global__ __launch_bounds__(256)
void gemm_out_kernel(const unsigned short* __restrict__ A, const unsigned short* __restrict__ W,
                     const float* __restrict__ bias, float* __restrict__ out) {
  __shared__ unsigned short As[128 * 32];
  __shared__ unsigned short Bs[128 * 32];
  int swz = (blockIdx.x & 7) * 64 + (blockIdx.x >> 3);
  gemm_body<0>(A, W, bias, nullptr, out, nullptr, 1024, 1024, swz, As, Bs);
}

// ---------------- flash attention (r13/r15-verified: depth-2 pipeline) ----------------
__global__ __launch_bounds__(256)
void flash_attn_kernel(const unsigned short* __restrict__ q,
                       const unsigned short* __restrict__ k,
                       const unsigned short* __restrict__ vt,
                       unsigned short* __restrict__ o) {
  // XCD-chunked bijective swizzle: 1024 wgs / 8 XCDs; each XCD owns 4 (h,b) pairs.
  const int bid = blockIdx.x;
  const int lin = (bid & 7) * 128 + (bid >> 3);
  const int qb = lin & 31;
  const int hb = lin >> 5;
  const int h = hb & 15, b = hb >> 4;

  const int tid = threadIdx.x;
  const int w = tid >> 6, lane = tid & 63;
  const int l31 = lane & 31, hi = lane >> 5;

  // double-buffered K [kv=64][d=64] and V^T [d=64][kv=64]; 16B-chunk XOR swizzle
  __shared__ unsigned short Ks[2][64 * 64];
  __shared__ unsigned short Vs[2][64 * 64];

  const size_t C = 1024;
  const int qrow = b * 4096 + qb * 128 + w * 32 + l31;   // this lane's q-row

  // Q (pre-scaled by SCL_L2E in projection) as MFMA B-operand
  bf16x8 qf[4];
#pragma unroll
  for (int ks = 0; ks < 4; ++ks)
    qf[ks] = *(const bf16x8*)(q + (size_t)qrow * C + h * 64 + ks * 16 + hi * 8);

  f32x16 o0 = (f32x16)0.0f, o1 = (f32x16)0.0f;   // O^T[d][q=l31], d-halves
  float lrun = 0.f;                              // per-half row-sum (merged at end)

  // ---- conflict-free staging map (r10-proven): 8-lane phase -> 8 rows ----
  const int srow = (tid & 7) | ((tid >> 5) << 3);   // 0..63
  const int sc2  = (tid >> 3) & 3;                  // 0..3
  const int sxor = (srow & 7);                      // chunk XOR for this row
  const unsigned short* kbase = k  + ((size_t)(b * 2048 + srow)) * C + h * 64;
  const unsigned short* vbase = vt + ((size_t)(b * 1024 + h * 64 + srow)) * 2048;

  const int r0 = l31, r1 = 32 + l31;
  const int x0c = (r0 & 7) * 8, x1c = (r1 & 7) * 8;

  // exp + T12 pack: s (pre-scaled scores) -> pw fragments; updates lrun
  auto exppack = [&](f32x16& s0, f32x16& s1, u32x4 (&pw)[4]) {
    float rs0 = 0.f, rs1 = 0.f;
#pragma unroll
    for (int i = 0; i < 16; ++i) {
      float p0 = FAST_EXP2(s0[i]);
      float p1 = FAST_EXP2(s1[i]);
      s0[i] = p0; s1[i] = p1;
      rs0 += p0; rs1 += p1;
    }
    lrun += rs0 + rs1;
#pragma unroll
    for (int hh = 0; hh < 2; ++hh) {
#pragma unroll
      for (int cp = 0; cp < 2; ++cp) {
#pragma unroll
        for (int e = 0; e < 2; ++e) {
          float xa0 = (hh == 0) ? s0[8 * cp + 2 * e]     : s1[8 * cp + 2 * e];
          float xa1 = (hh == 0) ? s0[8 * cp + 2 * e + 1] : s1[8 * cp + 2 * e + 1];
          float xb0 = (hh == 0) ? s0[8 * cp + 4 + 2 * e]     : s1[8 * cp + 4 + 2 * e];
          float xb1 = (hh == 0) ? s0[8 * cp + 4 + 2 * e + 1] : s1[8 * cp + 4 + 2 * e + 1];
          uint32_t wa = cvt_pk_bf16(xa0, xa1);
          uint32_t wb = cvt_pk_bf16(xb0, xb1);
          plane32_swap(wa, wb);
          pw[2 * hh + cp][e]     = wa;
          pw[2 * hh + cp][e + 2] = wb;
        }
      }
    }
  };

  bf16x8 krg[2], vrg[2], tmp[2];
  // prologue staging: K(0)->Ks[0], K(1)->Ks[1], V(0)->Vs[0]; regs K(2), V(1)
#pragma unroll
  for (int j = 0; j < 2; ++j) tmp[j] = *(const bf16x8*)(kbase + (sc2 + 4 * j) * 8);
#pragma unroll
  for (int j = 0; j < 2; ++j)
    *(bf16x8*)(&Ks[0][srow * 64 + (((sc2 + 4 * j) ^ sxor) * 8)]) = tmp[j];
#pragma unroll
  for (int j = 0; j < 2; ++j) tmp[j] = *(const bf16x8*)(kbase + (size_t)64 * C + (sc2 + 4 * j) * 8);
#pragma unroll
  for (int j = 0; j < 2; ++j)
    *(bf16x8*)(&Ks[1][srow * 64 + (((sc2 + 4 * j) ^ sxor) * 8)]) = tmp[j];
#pragma unroll
  for (int j = 0; j < 2; ++j) tmp[j] = *(const bf16x8*)(vbase + (sc2 + 4 * j) * 8);
#pragma unroll
  for (int j = 0; j < 2; ++j)
    *(bf16x8*)(&Vs[0][srow * 64 + (((sc2 + 4 * j) ^ sxor) * 8)]) = tmp[j];
#pragma unroll
  for (int j = 0; j < 2; ++j) {
    krg[j] = *(const bf16x8*)(kbase + (size_t)128 * C + (sc2 + 4 * j) * 8);
    vrg[j] = *(const bf16x8*)(vbase + 64 + (sc2 + 4 * j) * 8);
  }
  __syncthreads();

  // ---- prologue compute: QK(0) -> s; exp/pack(0) -> pwA ----
  u32x4 pwA[4], pwB[4];
  {
    f32x16 s0 = (f32x16)0.0f, s1 = (f32x16)0.0f;
    __builtin_amdgcn_s_setprio(1);
#pragma unroll
    for (int ks = 0; ks < 4; ++ks) {
      int coff = ks * 16 + hi * 8;
      bf16x8 kf0 = *(const bf16x8*)(&Ks[0][r0 * 64 + (coff ^ x0c)]);
      bf16x8 kf1 = *(const bf16x8*)(&Ks[0][r1 * 64 + (coff ^ x1c)]);
      s0 = __builtin_amdgcn_mfma_f32_32x32x16_bf16(kf0, qf[ks], s0, 0, 0, 0);
      s1 = __builtin_amdgcn_mfma_f32_32x32x16_bf16(kf1, qf[ks], s1, 0, 0, 0);
    }
    __builtin_amdgcn_s_setprio(0);
    exppack(s0, s1, pwA);
  }
  __syncthreads();   // all waves done reading Ks[0] before iter-0 stages K(2)

  // ---- depth-2 pipelined main loop (r13-verified) ----
  auto body = [&](int t, u32x4 (&pwC)[4], u32x4 (&pwN)[4]) {
    const unsigned short* Vc = Vs[t & 1];
    f32x16 s0 = (f32x16)0.0f, s1 = (f32x16)0.0f;

    __builtin_amdgcn_s_setprio(1);
    if (t < 31) {   // QK(t+1): reads Ks[(t+1)&1], untouched by iter-t staging
      const unsigned short* Kn = Ks[(t + 1) & 1];
#pragma unroll
      for (int ks = 0; ks < 4; ++ks) {
        int coff = ks * 16 + hi * 8;
        bf16x8 kf0 = *(const bf16x8*)(Kn + r0 * 64 + (coff ^ x0c));
        bf16x8 kf1 = *(const bf16x8*)(Kn + r1 * 64 + (coff ^ x1c));
        s0 = __builtin_amdgcn_mfma_f32_32x32x16_bf16(kf0, qf[ks], s0, 0, 0, 0);
        s1 = __builtin_amdgcn_mfma_f32_32x32x16_bf16(kf1, qf[ks], s1, 0, 0, 0);
      }
    }
    // PV(t): pwC packed last iteration -> no dependency on this iter's exp
#pragma unroll
    for (int ksv = 0; ksv < 4; ++ksv) {
      bf16x8 pv = __builtin_bit_cast(bf16x8, pwC[ksv]);
      int coff = ksv * 16 + hi * 8;
      bf16x8 vf0 = *(const bf16x8*)(Vc + r0 * 64 + (coff ^ x0c));
      bf16x8 vf1 = *(const bf16x8*)(Vc + r1 * 64 + (coff ^ x1c));
      o0 = __builtin_amdgcn_mfma_f32_32x32x16_bf16(vf0, pv, o0, 0, 0, 0);
      o1 = __builtin_amdgcn_mfma_f32_32x32x16_bf16(vf1, pv, o1, 0, 0, 0);
    }
    __builtin_amdgcn_s_setprio(0);

    // staging (r12/r13-verified cadence): K leads V by one tile
    if (t < 30) {
#pragma unroll
      for (int j = 0; j < 2; ++j)
        *(bf16x8*)(&((unsigned short*)Ks[t & 1])[srow * 64 + (((sc2 + 4 * j) ^ sxor) * 8)]) = krg[j];
    }
    if (t < 31) {
#pragma unroll
      for (int j = 0; j < 2; ++j)
        *(bf16x8*)(&((unsigned short*)Vs[(t + 1) & 1])[srow * 64 + (((sc2 + 4 * j) ^ sxor) * 8)]) = vrg[j];
    }
    if (t < 29) {
#pragma unroll
      for (int j = 0; j < 2; ++j)
        krg[j] = *(const bf16x8*)(kbase + (size_t)(t + 3) * 64 * C + (sc2 + 4 * j) * 8);
    }
    if (t < 30) {
#pragma unroll
      for (int j = 0; j < 2; ++j)
        vrg[j] = *(const bf16x8*)(vbase + (t + 2) * 64 + (sc2 + 4 * j) * 8);
    }

    // exp/pack(t+1): result needed only at next iter's PV
    if (t < 31) exppack(s0, s1, pwN);

    if (t < 31) __syncthreads();
  };

  for (int tt = 0; tt < 16; ++tt) {
    body(2 * tt,     pwA, pwB);
    body(2 * tt + 1, pwB, pwA);
  }

  // ---- epilogue: merge row-sum halves, normalize, redistribute, store ----
  float lsum = lrun + __shfl_xor(lrun, 32);   // single cross-half merge
  const float inv = 1.0f / lsum;
  u32x4 ow[4];
#pragma unroll
  for (int c = 0; c < 4; ++c) {
#pragma unroll
    for (int e = 0; e < 2; ++e) {
      uint32_t wa = cvt_pk_bf16(o0[4 * c + 2 * e] * inv, o0[4 * c + 2 * e + 1] * inv);
      uint32_t wb = cvt_pk_bf16(o1[4 * c + 2 * e] * inv, o1[4 * c + 2 * e + 1] * inv);
      plane32_swap(wa, wb);
      ow[c][e]     = wa;
      ow[c][e + 2] = wb;
    }
  }
  unsigned short* op = o + (size_t)qrow * C + h * 64 + hi * 32;
#pragma unroll
  for (int ch = 0; ch < 4; ++ch)
    *(u32x4*)(op + ch * 8) = ow[ch];
}

// ---------------------------------------------------------------------------
extern "C" void kernel_launch(void* const* d_in, const int* in_sizes, int n_in,
                              void* d_out, int out_size, void* d_ws, size_t ws_size,
                              hipStream_t stream) {
  const float* x   = (const float*)d_in[0];
  const float* q_w = (const float*)d_in[1];
  const float* q_b = (const float*)d_in[2];
  const float* k_w = (const float*)d_in[3];
  const float* k_b = (const float*)d_in[4];
  const float* v_w = (const float*)d_in[5];
  const float* v_b = (const float*)d_in[6];
  const float* cw  = (const float*)d_in[7];
  const float* cb  = (const float*)d_in[8];
  const float* o_w = (const float*)d_in[9];
  const float* o_b = (const float*)d_in[10];
  float* out = (float*)d_out;

  unsigned short* ws    = (unsigned short*)d_ws;
  unsigned short* x_bf  = ws;                    // 8388608 (2*4096*1024)
  unsigned short* qw_bf = x_bf + 8388608;        // 4x 1048576, contiguous
  unsigned short* kw_bf = qw_bf + 1048576;       // (qw,kw,vw,ow order)
  unsigned short* vw_bf = kw_bf + 1048576;
  unsigned short* ow_bf = vw_bf + 1048576;
  unsigned short* q_bf  = ow_bf + 1048576;       // 8388608
  unsigned short* xd_bf = q_bf + 8388608;        // 4194304 (2*2048*1024)
  unsigned short* k_bf  = xd_bf + 4194304;
  unsigned short* vt_bf = k_bf + 4194304;        // V^T [B*H, 64, 2048]
  unsigned short* ao_bf = x_bf;                  // alias: x_bf dead after q-GEMM

  WPtrs wp = {q_w, k_w, v_w, o_w};
  prep_kernel<<<6144, 256, 0, stream>>>(wp, qw_bf, x, cw, cb, xd_bf, x_bf);

  // merged q-GEMM + fused KV-GEMM: 1024 blocks -> 4 blocks/CU
  gemm_qkv_kernel<<<1024, 256, 0, stream>>>(x_bf, qw_bf, q_b, q_bf,
                                            xd_bf, kw_bf, k_b, v_b, k_bf, vt_bf);

  flash_attn_kernel<<<1024, 256, 0, stream>>>(q_bf, k_bf, vt_bf, ao_bf);

  gemm_out_kernel<<<512, 256, 0, stream>>>(ao_bf, ow_bf, o_b, out);
}